// Round 8
// baseline (172.534 us; speedup 1.0000x reference)
//
#include <hip/hip_runtime.h>
#include <math.h>

#define N_NODES 100000
#define N_EDGES 600000
#define DIM 128
#define LN_EPS 1e-5f
#define SCAN_NBLK ((N_NODES + 255) / 256)  // 391
#define NTILES ((N_NODES + 127) / 128)     // 782
#define NODE_GRID 256

typedef __bf16 bf16x8 __attribute__((ext_vector_type(8)));
typedef __bf16 bf16x4 __attribute__((ext_vector_type(4)));
typedef float f32x4 __attribute__((ext_vector_type(4)));

// ---------------- prep: h f32 -> bf16 (8 elems/thread), fused degree count ----------------
__global__ __launch_bounds__(256)
void prep_kernel(const float* __restrict__ h, const int* __restrict__ edst,
                 __bf16* __restrict__ h_bf, int* __restrict__ counts) {
  int i = blockIdx.x * 256 + threadIdx.x;  // 1,600,000 threads exactly
  {
    const float4 v0 = *reinterpret_cast<const float4*>(h + (size_t)i * 8);
    const float4 v1 = *reinterpret_cast<const float4*>(h + (size_t)i * 8 + 4);
    bf16x8 b;
    b[0] = (__bf16)v0.x; b[1] = (__bf16)v0.y; b[2] = (__bf16)v0.z; b[3] = (__bf16)v0.w;
    b[4] = (__bf16)v1.x; b[5] = (__bf16)v1.y; b[6] = (__bf16)v1.z; b[7] = (__bf16)v1.w;
    *reinterpret_cast<bf16x8*>(h_bf + (size_t)i * 8) = b;
  }
  if (i < N_EDGES) atomicAdd(&counts[edst[i]], 1);
}

// ---------------- CSR build ----------------
__global__ __launch_bounds__(256)
void scan1_kernel(const int* __restrict__ counts, int* __restrict__ block_sums) {
  int i = blockIdx.x * 256 + threadIdx.x;
  int v = (i < N_NODES) ? counts[i] : 0;
#pragma unroll
  for (int off = 1; off < 64; off <<= 1) v += __shfl_xor(v, off);
  __shared__ int ws[4];
  if ((threadIdx.x & 63) == 0) ws[threadIdx.x >> 6] = v;
  __syncthreads();
  if (threadIdx.x == 0) block_sums[blockIdx.x] = ws[0] + ws[1] + ws[2] + ws[3];
}

__global__ __launch_bounds__(512)
void scan2_kernel(int* __restrict__ block_sums) {
  __shared__ int sh[512];
  int t = threadIdx.x;
  int v = (t < SCAN_NBLK) ? block_sums[t] : 0;
  sh[t] = v;
  __syncthreads();
#pragma unroll
  for (int off = 1; off < 512; off <<= 1) {
    int u = (t >= off) ? sh[t - off] : 0;
    __syncthreads();
    sh[t] += u;
    __syncthreads();
  }
  if (t < SCAN_NBLK) block_sums[t] = (t == 0) ? 0 : sh[t - 1];
}

__global__ __launch_bounds__(256)
void scan3_kernel(const int* __restrict__ counts, const int* __restrict__ block_excl,
                  int* __restrict__ row_off, int* __restrict__ cursor) {
  int i = blockIdx.x * 256 + threadIdx.x;
  int t = threadIdx.x;
  int lane = t & 63, wv = t >> 6;
  int v = (i < N_NODES) ? counts[i] : 0;
  int s = v;
#pragma unroll
  for (int off = 1; off < 64; off <<= 1) {
    int u = __shfl_up(s, off);
    if (lane >= off) s += u;
  }
  __shared__ int wtot[4];
  if (lane == 63) wtot[wv] = s;
  __syncthreads();
  int wo = 0;
  for (int w = 0; w < wv; ++w) wo += wtot[w];
  int excl = block_excl[blockIdx.x] + wo + (s - v);
  if (i < N_NODES) { row_off[i] = excl; cursor[i] = 0; }
  if (i == 0) row_off[N_NODES] = N_EDGES;
}

__global__ __launch_bounds__(256)
void csr_fill_kernel(const int* __restrict__ esrc, const int* __restrict__ edst,
                     const int* __restrict__ row_off, int* __restrict__ cursor,
                     int* __restrict__ csr_src) {
  int base = (blockIdx.x * 256 + threadIdx.x) * 4;
  if (base >= N_EDGES) return;
  int4 s4 = *reinterpret_cast<const int4*>(esrc + base);
  int4 d4 = *reinterpret_cast<const int4*>(edst + base);
  {
    int pos = atomicAdd(&cursor[d4.x], 1);
    csr_src[row_off[d4.x] + pos] = s4.x;
  }
  {
    int pos = atomicAdd(&cursor[d4.y], 1);
    csr_src[row_off[d4.y] + pos] = s4.y;
  }
  {
    int pos = atomicAdd(&cursor[d4.z], 1);
    csr_src[row_off[d4.z] + pos] = s4.z;
  }
  {
    int pos = atomicAdd(&cursor[d4.w], 1);
    csr_src[row_off[d4.w] + pos] = s4.w;
  }
}

// ---------------- gather mean over bf16 h rows: 16 lanes x 16B per node ----------------
__global__ __launch_bounds__(256)
void gather_kernel(const __bf16* __restrict__ h_bf, const int* __restrict__ csr_src,
                   const int* __restrict__ row_off, __bf16* __restrict__ mean_bf) {
  int node = blockIdx.x * 16 + (threadIdx.x >> 4);
  if (node >= N_NODES) return;
  int t = threadIdx.x & 15;
  int b = row_off[node], e = row_off[node + 1];
  float acc[8];
#pragma unroll
  for (int j = 0; j < 8; ++j) acc[j] = 0.f;
  int i = b;
  for (; i + 4 <= e; i += 4) {
    int s0 = csr_src[i], s1 = csr_src[i + 1], s2 = csr_src[i + 2], s3 = csr_src[i + 3];
    bf16x8 v0 = *reinterpret_cast<const bf16x8*>(h_bf + (size_t)s0 * DIM + t * 8);
    bf16x8 v1 = *reinterpret_cast<const bf16x8*>(h_bf + (size_t)s1 * DIM + t * 8);
    bf16x8 v2 = *reinterpret_cast<const bf16x8*>(h_bf + (size_t)s2 * DIM + t * 8);
    bf16x8 v3 = *reinterpret_cast<const bf16x8*>(h_bf + (size_t)s3 * DIM + t * 8);
#pragma unroll
    for (int j = 0; j < 8; ++j)
      acc[j] += (float)v0[j] + (float)v1[j] + (float)v2[j] + (float)v3[j];
  }
  for (; i < e; ++i) {
    int s = csr_src[i];
    bf16x8 v = *reinterpret_cast<const bf16x8*>(h_bf + (size_t)s * DIM + t * 8);
#pragma unroll
    for (int j = 0; j < 8; ++j) acc[j] += (float)v[j];
  }
  float inv = (e > b) ? 1.0f / (float)(e - b) : 0.0f;
  bf16x8 mv;
#pragma unroll
  for (int j = 0; j < 8; ++j) mv[j] = (__bf16)(acc[j] * inv);
  *reinterpret_cast<bf16x8*>(mean_bf + (size_t)node * DIM + t * 8) = mv;
}

// ---------------- fused node kernel v5: A-layout epilogue + prefetch ----------------
// Strip round-trips only m and gate (C->A transpose). Epilogue runs in A-layout:
// h already in registers, LN row-sum = 2 shfl_xor, direct vectorized stores.
// Next-tile A-frags prefetched after pass1 (a_m/nacc dead -> regs free).
__global__ __launch_bounds__(512, 1)
void node_kernel(const __bf16* __restrict__ h_bf,
                 const __bf16* __restrict__ mean_bf,
                 const int* __restrict__ counts,
                 const float* __restrict__ Wself,
                 const float* __restrict__ Wneigh,
                 const float* __restrict__ Wgate,
                 const float* __restrict__ b_self,
                 const float* __restrict__ b_neigh,
                 const float* __restrict__ b_gate,
                 const float* __restrict__ ln_g,
                 const float* __restrict__ ln_b,
                 float* __restrict__ out) {
  __shared__ __align__(16) char smem[163840];
  char* Wl = smem;                       // 4 x 32768 B bf16 weights, XOR-swizzled

  const int tid = threadIdx.x;

  // ---- stage all 4 weight matrices: f32 global -> bf16 LDS ----
  for (int c = tid; c < 8192; c += 512) {
    int mi = c >> 11;
    int w = c & 2047;
    int row = w >> 4, col8 = w & 15;
    const float* src;
    if (mi == 0)      src = Wself  + row * 128 + col8 * 8;
    else if (mi == 1) src = Wneigh + row * 128 + col8 * 8;
    else if (mi == 2) src = Wgate  + row * 256 + col8 * 8;
    else              src = Wgate  + row * 256 + 128 + col8 * 8;
    float4 v0 = *reinterpret_cast<const float4*>(src);
    float4 v1 = *reinterpret_cast<const float4*>(src + 4);
    bf16x8 b;
    b[0] = (__bf16)v0.x; b[1] = (__bf16)v0.y; b[2] = (__bf16)v0.z; b[3] = (__bf16)v0.w;
    b[4] = (__bf16)v1.x; b[5] = (__bf16)v1.y; b[6] = (__bf16)v1.z; b[7] = (__bf16)v1.w;
    int byte = (row * 256 + col8 * 16) ^ ((row & 7) << 4);
    *reinterpret_cast<bf16x8*>(Wl + mi * 32768 + byte) = b;
  }
  __syncthreads();  // only barrier in the kernel

  const int lane = tid & 63;
  const int wave = tid >> 6;
  const int col = lane & 15;                       // A-row / C-col / epilogue-row
  const int kb = (lane >> 4) << 3;                 // k sub-offset 0,8,16,24
  const int rloc = (lane >> 4) << 2;               // C-layout local row base
  char* Ms = smem + 131072 + wave * 4096;          // wave-private strip: 16 x 256 B

  auto load_frags = [&](int tile, bf16x8* fh, bf16x8* fm) {
    int n_a = tile * 128 + wave * 16 + col;
    if (n_a < N_NODES) {
#pragma unroll
      for (int k0 = 0; k0 < 4; ++k0) {
        int koff = k0 * 32 + kb;
        fh[k0] = *reinterpret_cast<const bf16x8*>(h_bf + (size_t)n_a * DIM + koff);
        fm[k0] = *reinterpret_cast<const bf16x8*>(mean_bf + (size_t)n_a * DIM + koff);
      }
    } else {
#pragma unroll
      for (int k0 = 0; k0 < 4; ++k0)
#pragma unroll
        for (int j = 0; j < 8; ++j) { fh[k0][j] = (__bf16)0.f; fm[k0][j] = (__bf16)0.f; }
    }
  };

  bf16x8 a_h[4], a_m[4];
  load_frags(blockIdx.x, a_h, a_m);

  for (int tile = blockIdx.x; tile < NTILES; tile += NODE_GRID) {
    const int node0 = tile * 128;
    const int next = tile + NODE_GRID;

    // predecessor flags for the C-layout combine (rows rloc..rloc+3)
    int4 c4 = *reinterpret_cast<const int4*>(counts + node0 + wave * 16 + rloc);
    float hp[4];
    {
      int nb0 = node0 + wave * 16 + rloc;
      hp[0] = (nb0 + 0 < N_NODES && c4.x > 0) ? 1.f : 0.f;
      hp[1] = (nb0 + 1 < N_NODES && c4.y > 0) ? 1.f : 0.f;
      hp[2] = (nb0 + 2 < N_NODES && c4.z > 0) ? 1.f : 0.f;
      hp[3] = (nb0 + 3 < N_NODES && c4.w > 0) ? 1.f : 0.f;
    }

    // ---- PASS 1: hs = h@Wself^T, hn = mean@Wneigh^T ----
    f32x4 sacc[8], nacc[8];
#pragma unroll
    for (int i = 0; i < 8; ++i) {
      sacc[i] = (f32x4){0.f, 0.f, 0.f, 0.f};
      nacc[i] = (f32x4){0.f, 0.f, 0.f, 0.f};
    }
#pragma unroll
    for (int k0 = 0; k0 < 4; ++k0) {
      int koff2 = (k0 * 32 + kb) * 2;
#pragma unroll
      for (int nb = 0; nb < 8; ++nb) {
        int row = nb * 16 + col;
        int swz = (row * 256 + koff2) ^ ((row & 7) << 4);
        bf16x8 bs = *reinterpret_cast<const bf16x8*>(Wl + swz);
        bf16x8 bn = *reinterpret_cast<const bf16x8*>(Wl + 32768 + swz);
        sacc[nb] = __builtin_amdgcn_mfma_f32_16x16x32_bf16(a_h[k0], bs, sacc[nb], 0, 0, 0);
        nacc[nb] = __builtin_amdgcn_mfma_f32_16x16x32_bf16(a_m[k0], bn, nacc[nb], 0, 0, 0);
      }
    }

    // ---- combine (C-layout): m = hs + b_self + hp*(hn + b_neigh) -> strip bf16 ----
#pragma unroll
    for (int nb = 0; nb < 8; ++nb) {
      int d = nb * 16 + col;
      float bs = b_self[d], bn = b_neigh[d];
#pragma unroll
      for (int r = 0; r < 4; ++r) {
        float mval = sacc[nb][r] + bs + hp[r] * (nacc[nb][r] + bn);
        int rl = rloc + r;
        int byte = (rl * 256 + d * 2) ^ ((rl & 7) << 4);
        *reinterpret_cast<__bf16*>(Ms + byte) = (__bf16)mval;
      }
    }
    // sacc/nacc/a_m dead -> issue next-tile prefetch now (in flight thru pass2+epilogue)
    bf16x8 p_h[4], p_m[4];
    if (next < NTILES) load_frags(next, p_h, p_m);

    // ---- PASS 2: gate = h@Wgh^T + m@Wgm^T (m read back in A-layout) ----
    bf16x8 am2[4];
    f32x4 gacc[8];
#pragma unroll
    for (int i = 0; i < 8; ++i) gacc[i] = (f32x4){0.f, 0.f, 0.f, 0.f};
#pragma unroll
    for (int k0 = 0; k0 < 4; ++k0) {
      int koff2 = (k0 * 32 + kb) * 2;
      int abyte = (col * 256 + koff2) ^ ((col & 7) << 4);
      am2[k0] = *reinterpret_cast<const bf16x8*>(Ms + abyte);
#pragma unroll
      for (int nb = 0; nb < 8; ++nb) {
        int row = nb * 16 + col;
        int swz = (row * 256 + koff2) ^ ((row & 7) << 4);
        bf16x8 bgh = *reinterpret_cast<const bf16x8*>(Wl + 65536 + swz);
        bf16x8 bgm = *reinterpret_cast<const bf16x8*>(Wl + 98304 + swz);
        gacc[nb] = __builtin_amdgcn_mfma_f32_16x16x32_bf16(a_h[k0], bgh, gacc[nb], 0, 0, 0);
        gacc[nb] = __builtin_amdgcn_mfma_f32_16x16x32_bf16(am2[k0], bgm, gacc[nb], 0, 0, 0);
      }
    }

    // ---- gate C-layout -> strip -> A-layout (same-wave in-order DS) ----
#pragma unroll
    for (int nb = 0; nb < 8; ++nb) {
      int d = nb * 16 + col;
#pragma unroll
      for (int r = 0; r < 4; ++r) {
        int rl = rloc + r;
        int byte = (rl * 256 + d * 2) ^ ((rl & 7) << 4);
        *reinterpret_cast<__bf16*>(Ms + byte) = (__bf16)gacc[nb][r];
      }
    }
    bf16x8 gt[4];
#pragma unroll
    for (int k0 = 0; k0 < 4; ++k0) {
      int abyte = (col * 256 + (k0 * 32 + kb) * 2) ^ ((col & 7) << 4);
      gt[k0] = *reinterpret_cast<const bf16x8*>(Ms + abyte);
    }

    // ---- epilogue in A-layout: row = col, cols = k0*32+kb+j; h/m already in regs ----
    float s1 = 0.f, s2 = 0.f;
    bf16x8 vb[4];
#pragma unroll
    for (int k0 = 0; k0 < 4; ++k0) {
      int c0 = k0 * 32 + kb;
      float4 bg0 = *reinterpret_cast<const float4*>(b_gate + c0);
      float4 bg1 = *reinterpret_cast<const float4*>(b_gate + c0 + 4);
      float bgv[8] = {bg0.x, bg0.y, bg0.z, bg0.w, bg1.x, bg1.y, bg1.z, bg1.w};
#pragma unroll
      for (int j = 0; j < 8; ++j) {
        float g = 1.0f / (1.0f + __expf(-((float)gt[k0][j] + bgv[j])));
        float v = g * (float)am2[k0][j] + (1.0f - g) * (float)a_h[k0][j];
        s1 += v;
        s2 += v * v;
        vb[k0][j] = (__bf16)v;
      }
    }
    s1 += __shfl_xor(s1, 16); s1 += __shfl_xor(s1, 32);
    s2 += __shfl_xor(s2, 16); s2 += __shfl_xor(s2, 32);
    float mu = s1 * (1.0f / DIM);
    float var = s2 * (1.0f / DIM) - mu * mu;
    float rs = rsqrtf(var + LN_EPS);

    {
      int gn = node0 + wave * 16 + col;
      bool valid = gn < N_NODES;
#pragma unroll
      for (int k0 = 0; k0 < 4; ++k0) {
        int c0 = k0 * 32 + kb;
        float4 g0 = *reinterpret_cast<const float4*>(ln_g + c0);
        float4 g1 = *reinterpret_cast<const float4*>(ln_g + c0 + 4);
        float4 e0 = *reinterpret_cast<const float4*>(ln_b + c0);
        float4 e1 = *reinterpret_cast<const float4*>(ln_b + c0 + 4);
        float4 o0, o1;
        o0.x = fmaxf(((float)vb[k0][0] - mu) * rs * g0.x + e0.x, 0.f);
        o0.y = fmaxf(((float)vb[k0][1] - mu) * rs * g0.y + e0.y, 0.f);
        o0.z = fmaxf(((float)vb[k0][2] - mu) * rs * g0.z + e0.z, 0.f);
        o0.w = fmaxf(((float)vb[k0][3] - mu) * rs * g0.w + e0.w, 0.f);
        o1.x = fmaxf(((float)vb[k0][4] - mu) * rs * g1.x + e1.x, 0.f);
        o1.y = fmaxf(((float)vb[k0][5] - mu) * rs * g1.y + e1.y, 0.f);
        o1.z = fmaxf(((float)vb[k0][6] - mu) * rs * g1.z + e1.z, 0.f);
        o1.w = fmaxf(((float)vb[k0][7] - mu) * rs * g1.w + e1.w, 0.f);
        if (valid) {
          *reinterpret_cast<float4*>(out + (size_t)gn * DIM + c0) = o0;
          *reinterpret_cast<float4*>(out + (size_t)gn * DIM + c0 + 4) = o1;
        }
      }
    }

    // ---- rotate prefetched fragments ----
    if (next < NTILES) {
#pragma unroll
      for (int k0 = 0; k0 < 4; ++k0) { a_h[k0] = p_h[k0]; a_m[k0] = p_m[k0]; }
    }
  }
}

extern "C" void kernel_launch(void* const* d_in, const int* in_sizes, int n_in,
                              void* d_out, int out_size, void* d_ws, size_t ws_size,
                              hipStream_t stream) {
  const float* h      = (const float*)d_in[0];
  const int*   esrc   = (const int*)d_in[1];
  const int*   edst   = (const int*)d_in[2];
  const float* Wself  = (const float*)d_in[3];
  const float* bself  = (const float*)d_in[4];
  const float* Wneigh = (const float*)d_in[5];
  const float* bneigh = (const float*)d_in[6];
  const float* Wgate  = (const float*)d_in[7];
  const float* bgate  = (const float*)d_in[8];
  const float* ln_g   = (const float*)d_in[9];
  const float* ln_b   = (const float*)d_in[10];
  float* out = (float*)d_out;

  char* ws = (char*)d_ws;
  int* counts   = (int*)ws;                      // 400,000 B
  int* row_off  = (int*)(ws + 400384);           // 400,004 B
  int* cursor   = (int*)(ws + 800768);           // 400,000 B
  int* csr_src  = (int*)(ws + 1200768);          // 2,400,000 B
  int* blk_sums = (int*)(ws + 3600768);          // 1,564 B
  __bf16* h_bf    = (__bf16*)(ws + 3602432);     // 25,600,000 B
  __bf16* mean_bf = (__bf16*)(ws + 29202432);    // 25,600,000 B

  hipMemsetAsync(counts, 0, (size_t)N_NODES * sizeof(int), stream);

  prep_kernel<<<6250, 256, 0, stream>>>(h, edst, h_bf, counts);
  scan1_kernel<<<SCAN_NBLK, 256, 0, stream>>>(counts, blk_sums);
  scan2_kernel<<<1, 512, 0, stream>>>(blk_sums);
  scan3_kernel<<<SCAN_NBLK, 256, 0, stream>>>(counts, blk_sums, row_off, cursor);
  csr_fill_kernel<<<(N_EDGES / 4 + 255) / 256, 256, 0, stream>>>(esrc, edst, row_off, cursor, csr_src);
  gather_kernel<<<(N_NODES + 15) / 16, 256, 0, stream>>>(h_bf, csr_src, row_off, mean_bf);
  node_kernel<<<NODE_GRID, 512, 0, stream>>>(
      h_bf, mean_bf, counts, Wself, Wneigh, Wgate,
      bself, bneigh, bgate, ln_g, ln_b, out);
}

// Round 9
// 154.271 us; speedup vs baseline: 1.1184x; 1.1184x over previous
//
#include <hip/hip_runtime.h>
#include <math.h>

#define N_NODES 100000
#define N_EDGES 600000
#define DIM 128
#define LN_EPS 1e-5f
#define SCAN_NBLK ((N_NODES + 255) / 256)  // 391
#define NTILES ((N_NODES + 127) / 128)     // 782
#define NODE_GRID 256

typedef __bf16 bf16x8 __attribute__((ext_vector_type(8)));
typedef __bf16 bf16x4 __attribute__((ext_vector_type(4)));
typedef float f32x4 __attribute__((ext_vector_type(4)));

// ---------------- prep: h f32 -> bf16 (8 elems/thread), fused degree count ----------------
__global__ __launch_bounds__(256)
void prep_kernel(const float* __restrict__ h, const int* __restrict__ edst,
                 __bf16* __restrict__ h_bf, int* __restrict__ counts) {
  int i = blockIdx.x * 256 + threadIdx.x;  // 1,600,000 threads exactly
  {
    const float4 v0 = *reinterpret_cast<const float4*>(h + (size_t)i * 8);
    const float4 v1 = *reinterpret_cast<const float4*>(h + (size_t)i * 8 + 4);
    bf16x8 b;
    b[0] = (__bf16)v0.x; b[1] = (__bf16)v0.y; b[2] = (__bf16)v0.z; b[3] = (__bf16)v0.w;
    b[4] = (__bf16)v1.x; b[5] = (__bf16)v1.y; b[6] = (__bf16)v1.z; b[7] = (__bf16)v1.w;
    *reinterpret_cast<bf16x8*>(h_bf + (size_t)i * 8) = b;
  }
  if (i < N_EDGES) atomicAdd(&counts[edst[i]], 1);
}

// ---------------- CSR build ----------------
// phase 1: per-block sums of counts
__global__ __launch_bounds__(256)
void scan1_kernel(const int* __restrict__ counts, int* __restrict__ block_sums) {
  int i = blockIdx.x * 256 + threadIdx.x;
  int v = (i < N_NODES) ? counts[i] : 0;
#pragma unroll
  for (int off = 1; off < 64; off <<= 1) v += __shfl_xor(v, off);
  __shared__ int ws[4];
  if ((threadIdx.x & 63) == 0) ws[threadIdx.x >> 6] = v;
  __syncthreads();
  if (threadIdx.x == 0) block_sums[blockIdx.x] = ws[0] + ws[1] + ws[2] + ws[3];
}

// phase 2 (fused former scan2+scan3): block computes its own exclusive base by
// reducing block_sums[0..blockIdx-1], then in-block exclusive scan -> row_off.
__global__ __launch_bounds__(256)
void scan3_kernel(const int* __restrict__ counts, const int* __restrict__ block_sums,
                  int* __restrict__ row_off, int* __restrict__ cursor) {
  const int i = blockIdx.x * 256 + threadIdx.x;
  const int t = threadIdx.x;
  const int lane = t & 63, wv = t >> 6;
  __shared__ int wtot[4];
  __shared__ int sbase[4];

  // exclusive base = sum of block_sums[0..blockIdx.x-1]
  int partial = 0;
  for (int j = t; j < blockIdx.x; j += 256) partial += block_sums[j];
#pragma unroll
  for (int off = 1; off < 64; off <<= 1) partial += __shfl_xor(partial, off);
  if (lane == 0) sbase[wv] = partial;
  __syncthreads();
  const int base = sbase[0] + sbase[1] + sbase[2] + sbase[3];

  int v = (i < N_NODES) ? counts[i] : 0;
  int s = v;
#pragma unroll
  for (int off = 1; off < 64; off <<= 1) {
    int u = __shfl_up(s, off);
    if (lane >= off) s += u;
  }
  if (lane == 63) wtot[wv] = s;
  __syncthreads();
  int wo = 0;
  for (int w = 0; w < wv; ++w) wo += wtot[w];
  int excl = base + wo + (s - v);
  if (i < N_NODES) { row_off[i] = excl; cursor[i] = 0; }
  if (i == 0) row_off[N_NODES] = N_EDGES;
}

__global__ __launch_bounds__(256)
void csr_fill_kernel(const int* __restrict__ esrc, const int* __restrict__ edst,
                     const int* __restrict__ row_off, int* __restrict__ cursor,
                     int* __restrict__ csr_src) {
  int base = (blockIdx.x * 256 + threadIdx.x) * 4;
  if (base >= N_EDGES) return;
  int4 s4 = *reinterpret_cast<const int4*>(esrc + base);
  int4 d4 = *reinterpret_cast<const int4*>(edst + base);
  {
    int pos = atomicAdd(&cursor[d4.x], 1);
    csr_src[row_off[d4.x] + pos] = s4.x;
  }
  {
    int pos = atomicAdd(&cursor[d4.y], 1);
    csr_src[row_off[d4.y] + pos] = s4.y;
  }
  {
    int pos = atomicAdd(&cursor[d4.z], 1);
    csr_src[row_off[d4.z] + pos] = s4.z;
  }
  {
    int pos = atomicAdd(&cursor[d4.w], 1);
    csr_src[row_off[d4.w] + pos] = s4.w;
  }
}

// ---------------- gather mean: 16 lanes x 16B per node, batch-8 rows in flight ----------------
__global__ __launch_bounds__(256)
void gather_kernel(const __bf16* __restrict__ h_bf, const int* __restrict__ csr_src,
                   const int* __restrict__ row_off, __bf16* __restrict__ mean_bf) {
  int node = blockIdx.x * 16 + (threadIdx.x >> 4);
  if (node >= N_NODES) return;
  int t = threadIdx.x & 15;
  int b = row_off[node], e = row_off[node + 1];
  float acc[8];
#pragma unroll
  for (int j = 0; j < 8; ++j) acc[j] = 0.f;
  for (int i = b; i < e; i += 8) {
    // up to 8 neighbor rows in flight: one idx round + one data round
    int idx[8];
#pragma unroll
    for (int j = 0; j < 8; ++j) idx[j] = (i + j < e) ? csr_src[i + j] : -1;
    bf16x8 v[8];
#pragma unroll
    for (int j = 0; j < 8; ++j) {
      if (idx[j] >= 0)
        v[j] = *reinterpret_cast<const bf16x8*>(h_bf + (size_t)idx[j] * DIM + t * 8);
      else
#pragma unroll
        for (int k = 0; k < 8; ++k) v[j][k] = (__bf16)0.f;
    }
#pragma unroll
    for (int j = 0; j < 8; ++j)
#pragma unroll
      for (int k = 0; k < 8; ++k) acc[k] += (float)v[j][k];
  }
  float inv = (e > b) ? 1.0f / (float)(e - b) : 0.0f;
  bf16x8 mv;
#pragma unroll
  for (int j = 0; j < 8; ++j) mv[j] = (__bf16)(acc[j] * inv);
  *reinterpret_cast<bf16x8*>(mean_bf + (size_t)node * DIM + t * 8) = mv;
}

// ---------------- fused node kernel v4 (R7 verbatim): two-pass GEMM, fits 128 VGPRs ----------------
// Pass 1: sacc(hs) + nacc(hn) over Wself/Wneigh -> combine to m (frees nacc),
//         m -> wave-private strip.
// Pass 2: gacc = h@Wgh^T + m@Wgm^T (m via strip transpose read).
// Peak live < 128 -> no scratch spill. Do NOT add prefetch or A-layout epilogue:
// both push peak live past 128 and the allocator spills (R5/R6/R8 regressions,
// visible as ~15-40 MB phantom FETCH/WRITE).
__global__ __launch_bounds__(512, 1)
void node_kernel(const __bf16* __restrict__ h_bf,
                 const __bf16* __restrict__ mean_bf,
                 const int* __restrict__ counts,
                 const float* __restrict__ Wself,
                 const float* __restrict__ Wneigh,
                 const float* __restrict__ Wgate,
                 const float* __restrict__ b_self,
                 const float* __restrict__ b_neigh,
                 const float* __restrict__ b_gate,
                 const float* __restrict__ ln_g,
                 const float* __restrict__ ln_b,
                 float* __restrict__ out) {
  __shared__ __align__(16) char smem[163840];
  char* Wl = smem;                       // 4 x 32768 B bf16 weights, XOR-swizzled

  const int tid = threadIdx.x;

  // ---- stage all 4 weight matrices: f32 global -> bf16 LDS ----
  for (int c = tid; c < 8192; c += 512) {
    int mi = c >> 11;
    int w = c & 2047;
    int row = w >> 4, col8 = w & 15;
    const float* src;
    if (mi == 0)      src = Wself  + row * 128 + col8 * 8;
    else if (mi == 1) src = Wneigh + row * 128 + col8 * 8;
    else if (mi == 2) src = Wgate  + row * 256 + col8 * 8;
    else              src = Wgate  + row * 256 + 128 + col8 * 8;
    float4 v0 = *reinterpret_cast<const float4*>(src);
    float4 v1 = *reinterpret_cast<const float4*>(src + 4);
    bf16x8 b;
    b[0] = (__bf16)v0.x; b[1] = (__bf16)v0.y; b[2] = (__bf16)v0.z; b[3] = (__bf16)v0.w;
    b[4] = (__bf16)v1.x; b[5] = (__bf16)v1.y; b[6] = (__bf16)v1.z; b[7] = (__bf16)v1.w;
    int byte = (row * 256 + col8 * 16) ^ ((row & 7) << 4);
    *reinterpret_cast<bf16x8*>(Wl + mi * 32768 + byte) = b;
  }
  __syncthreads();  // only barrier in the kernel

  const int lane = tid & 63;
  const int wave = tid >> 6;
  const int col = lane & 15;
  const int kb = (lane >> 4) << 3;                 // 0,8,16,24
  const int rloc = (lane >> 4) << 2;               // local acc row base (0,4,8,12)
  char* Ms = smem + 131072 + wave * 4096;          // wave-private strip: 16 rows x 256 B

  for (int tile = blockIdx.x; tile < NTILES; tile += NODE_GRID) {
    const int node0 = tile * 128;

    // ---- A fragments for this tile ----
    bf16x8 a_h[4], a_m[4];
    {
      int n_a = node0 + wave * 16 + col;
      if (n_a < N_NODES) {
#pragma unroll
        for (int k0 = 0; k0 < 4; ++k0) {
          int koff = k0 * 32 + kb;
          a_h[k0] = *reinterpret_cast<const bf16x8*>(h_bf + (size_t)n_a * DIM + koff);
          a_m[k0] = *reinterpret_cast<const bf16x8*>(mean_bf + (size_t)n_a * DIM + koff);
        }
      } else {
#pragma unroll
        for (int k0 = 0; k0 < 4; ++k0)
#pragma unroll
          for (int j = 0; j < 8; ++j) { a_h[k0][j] = (__bf16)0.f; a_m[k0][j] = (__bf16)0.f; }
      }
    }

    // predecessor flags (single int4 load)
    int4 c4 = *reinterpret_cast<const int4*>(counts + node0 + wave * 16 + rloc);
    float hp[4];
    {
      int nb0 = node0 + wave * 16 + rloc;
      hp[0] = (nb0 + 0 < N_NODES && c4.x > 0) ? 1.f : 0.f;
      hp[1] = (nb0 + 1 < N_NODES && c4.y > 0) ? 1.f : 0.f;
      hp[2] = (nb0 + 2 < N_NODES && c4.z > 0) ? 1.f : 0.f;
      hp[3] = (nb0 + 3 < N_NODES && c4.w > 0) ? 1.f : 0.f;
    }

    // ---- PASS 1: hs = h@Wself^T, hn = mean@Wneigh^T ----
    f32x4 sacc[8], nacc[8];
#pragma unroll
    for (int i = 0; i < 8; ++i) {
      sacc[i] = (f32x4){0.f, 0.f, 0.f, 0.f};
      nacc[i] = (f32x4){0.f, 0.f, 0.f, 0.f};
    }
#pragma unroll
    for (int k0 = 0; k0 < 4; ++k0) {
      int koff2 = (k0 * 32 + kb) * 2;
#pragma unroll
      for (int nb = 0; nb < 8; ++nb) {
        int row = nb * 16 + col;
        int swz = (row * 256 + koff2) ^ ((row & 7) << 4);
        bf16x8 bs = *reinterpret_cast<const bf16x8*>(Wl + swz);
        bf16x8 bn = *reinterpret_cast<const bf16x8*>(Wl + 32768 + swz);
        sacc[nb] = __builtin_amdgcn_mfma_f32_16x16x32_bf16(a_h[k0], bs, sacc[nb], 0, 0, 0);
        nacc[nb] = __builtin_amdgcn_mfma_f32_16x16x32_bf16(a_m[k0], bn, nacc[nb], 0, 0, 0);
      }
    }

    // ---- m = hs + b_self + has_pred*(hn + b_neigh); m -> strip (bf16); nacc dies ----
#pragma unroll
    for (int nb = 0; nb < 8; ++nb) {
      int d = nb * 16 + col;
      float bs = b_self[d], bn = b_neigh[d];
#pragma unroll
      for (int r = 0; r < 4; ++r) {
        float mval = sacc[nb][r] + bs + hp[r] * (nacc[nb][r] + bn);
        sacc[nb][r] = mval;  // sacc now holds m
        int rl = rloc + r;
        int byte = (rl * 256 + d * 2) ^ ((rl & 7) << 4);
        *reinterpret_cast<__bf16*>(Ms + byte) = (__bf16)mval;
      }
    }

    // ---- PASS 2: gate = h@Wgh^T + m@Wgm^T (m via strip, same-wave in-order DS) ----
    f32x4 gacc[8];
#pragma unroll
    for (int i = 0; i < 8; ++i) gacc[i] = (f32x4){0.f, 0.f, 0.f, 0.f};
#pragma unroll
    for (int k0 = 0; k0 < 4; ++k0) {
      int koff2 = (k0 * 32 + kb) * 2;
      int abyte = (col * 256 + koff2) ^ ((col & 7) << 4);
      bf16x8 am2 = *reinterpret_cast<const bf16x8*>(Ms + abyte);
#pragma unroll
      for (int nb = 0; nb < 8; ++nb) {
        int row = nb * 16 + col;
        int swz = (row * 256 + koff2) ^ ((row & 7) << 4);
        bf16x8 bgh = *reinterpret_cast<const bf16x8*>(Wl + 65536 + swz);
        bf16x8 bgm = *reinterpret_cast<const bf16x8*>(Wl + 98304 + swz);
        gacc[nb] = __builtin_amdgcn_mfma_f32_16x16x32_bf16(a_h[k0], bgh, gacc[nb], 0, 0, 0);
        gacc[nb] = __builtin_amdgcn_mfma_f32_16x16x32_bf16(am2, bgm, gacc[nb], 0, 0, 0);
      }
    }

    // ---- h fragments -> strip (overwrites m; same-wave DS ops are in-order) ----
#pragma unroll
    for (int k0 = 0; k0 < 4; ++k0) {
      int byte = (col * 256 + (k0 * 32 + kb) * 2) ^ ((col & 7) << 4);
      *reinterpret_cast<bf16x8*>(Ms + byte) = a_h[k0];
    }

    // ---- epilogue: g, v (h from strip), LN stats; v -> strip in place ----
    float s1[4] = {0.f, 0.f, 0.f, 0.f}, s2[4] = {0.f, 0.f, 0.f, 0.f};
#pragma unroll
    for (int nb = 0; nb < 8; ++nb) {
      int d = nb * 16 + col;
      float bg = b_gate[d];
#pragma unroll
      for (int r = 0; r < 4; ++r) {
        int rl = rloc + r;
        int byte = (rl * 256 + d * 2) ^ ((rl & 7) << 4);
        float hval = (float)*reinterpret_cast<const __bf16*>(Ms + byte);
        float g = 1.0f / (1.0f + __expf(-(gacc[nb][r] + bg)));
        float v = g * sacc[nb][r] + (1.0f - g) * hval;
        s1[r] += v;
        s2[r] += v * v;
        *reinterpret_cast<__bf16*>(Ms + byte) = (__bf16)v;  // element-private slot
      }
    }
#pragma unroll
    for (int off = 1; off < 16; off <<= 1) {
#pragma unroll
      for (int r = 0; r < 4; ++r) {
        s1[r] += __shfl_xor(s1[r], off);
        s2[r] += __shfl_xor(s2[r], off);
      }
    }
    float mu[4], rs[4];
#pragma unroll
    for (int r = 0; r < 4; ++r) {
      mu[r] = s1[r] * (1.0f / DIM);
      float var = s2[r] * (1.0f / DIM) - mu[r] * mu[r];
      rs[r] = rsqrtf(var + LN_EPS);
    }

    // ---- readback v (transposed), LN + relu, vectorized stores ----
    {
      int orow = lane >> 2;                  // local row 0..15
      int ochunk = lane & 3;
      int gn = node0 + wave * 16 + orow;
      int rsel = orow & 3;
      float muv = (rsel & 2) ? ((rsel & 1) ? mu[3] : mu[2]) : ((rsel & 1) ? mu[1] : mu[0]);
      float rsv = (rsel & 2) ? ((rsel & 1) ? rs[3] : rs[2]) : ((rsel & 1) ? rs[1] : rs[0]);
      bool valid = gn < N_NODES;
#pragma unroll
      for (int j = 0; j < 4; ++j) {
        int d0 = ochunk * 8 + j * 32;
        int byte = (orow * 256 + d0 * 2) ^ ((orow & 7) << 4);
        bf16x8 vb = *reinterpret_cast<const bf16x8*>(Ms + byte);
        float4 g0 = *reinterpret_cast<const float4*>(ln_g + d0);
        float4 g1 = *reinterpret_cast<const float4*>(ln_g + d0 + 4);
        float4 e0 = *reinterpret_cast<const float4*>(ln_b + d0);
        float4 e1 = *reinterpret_cast<const float4*>(ln_b + d0 + 4);
        float4 o0, o1;
        o0.x = fmaxf(((float)vb[0] - muv) * rsv * g0.x + e0.x, 0.f);
        o0.y = fmaxf(((float)vb[1] - muv) * rsv * g0.y + e0.y, 0.f);
        o0.z = fmaxf(((float)vb[2] - muv) * rsv * g0.z + e0.z, 0.f);
        o0.w = fmaxf(((float)vb[3] - muv) * rsv * g0.w + e0.w, 0.f);
        o1.x = fmaxf(((float)vb[4] - muv) * rsv * g1.x + e1.x, 0.f);
        o1.y = fmaxf(((float)vb[5] - muv) * rsv * g1.y + e1.y, 0.f);
        o1.z = fmaxf(((float)vb[6] - muv) * rsv * g1.z + e1.z, 0.f);
        o1.w = fmaxf(((float)vb[7] - muv) * rsv * g1.w + e1.w, 0.f);
        if (valid) {
          *reinterpret_cast<float4*>(out + (size_t)gn * DIM + d0) = o0;
          *reinterpret_cast<float4*>(out + (size_t)gn * DIM + d0 + 4) = o1;
        }
      }
    }
  }
}

extern "C" void kernel_launch(void* const* d_in, const int* in_sizes, int n_in,
                              void* d_out, int out_size, void* d_ws, size_t ws_size,
                              hipStream_t stream) {
  const float* h      = (const float*)d_in[0];
  const int*   esrc   = (const int*)d_in[1];
  const int*   edst   = (const int*)d_in[2];
  const float* Wself  = (const float*)d_in[3];
  const float* bself  = (const float*)d_in[4];
  const float* Wneigh = (const float*)d_in[5];
  const float* bneigh = (const float*)d_in[6];
  const float* Wgate  = (const float*)d_in[7];
  const float* bgate  = (const float*)d_in[8];
  const float* ln_g   = (const float*)d_in[9];
  const float* ln_b   = (const float*)d_in[10];
  float* out = (float*)d_out;

  char* ws = (char*)d_ws;
  int* counts   = (int*)ws;                      // 400,000 B
  int* row_off  = (int*)(ws + 400384);           // 400,004 B
  int* cursor   = (int*)(ws + 800768);           // 400,000 B
  int* csr_src  = (int*)(ws + 1200768);          // 2,400,000 B
  int* blk_sums = (int*)(ws + 3600768);          // 1,564 B
  __bf16* h_bf    = (__bf16*)(ws + 3602432);     // 25,600,000 B
  __bf16* mean_bf = (__bf16*)(ws + 29202432);    // 25,600,000 B

  hipMemsetAsync(counts, 0, (size_t)N_NODES * sizeof(int), stream);

  prep_kernel<<<6250, 256, 0, stream>>>(h, edst, h_bf, counts);
  scan1_kernel<<<SCAN_NBLK, 256, 0, stream>>>(counts, blk_sums);
  scan3_kernel<<<SCAN_NBLK, 256, 0, stream>>>(counts, blk_sums, row_off, cursor);
  csr_fill_kernel<<<(N_EDGES / 4 + 255) / 256, 256, 0, stream>>>(esrc, edst, row_off, cursor, csr_src);
  gather_kernel<<<(N_NODES + 15) / 16, 256, 0, stream>>>(h_bf, csr_src, row_off, mean_bf);
  node_kernel<<<NODE_GRID, 512, 0, stream>>>(
      h_bf, mean_bf, counts, Wself, Wneigh, Wgate,
      bself, bneigh, bgate, ln_g, ln_b, out);
}